// Round 7
// baseline (212.871 us; speedup 1.0000x reference)
//
#include <hip/hip_runtime.h>
#include <hip/hip_bf16.h>

// MSSA: x(8,2048,512) -> qkv = x@Wqkv ; scores = (q*s)@(k*s)^T over FULL 512 dims ;
// attn = softmax ; out = attn@v ; result = (out + x)@Wout + bout
//
// All GEMMs: 256x128-tile template, 4 waves each owning 128x64 (acc 8x4 of 16x16x32
// frags = 128 VGPR). 85 FLOP per LDS-read byte (vs 32 for the R6 64x64/wave template,
// which measured LDS-BW-bound at MfmaUtil 24%).
// __launch_bounds__(256,2): on this toolchain 2nd arg = min BLOCKS/CU (R3 lesson)
// -> 2 blocks x 4 waves / 4 SIMD = 2 waves/SIMD -> 256-VGPR cap, no spill at ~230.
//
// Workspace (128 MiB):
//   qkvb : bf16 [16384][1536]  q(x0.125)|k(x0.125)|v ; v-cols dead after transpose_v
//                              -> reused for res = bf16(attn_out + x)
//   VT   : bf16 [512][16384]   V transposed; dead after pvgemm -> reused for WoutT
//   S    : bf16 [8][2048][2048] scores/P; pre-sgemm holds xb (16.8MB) + WT (1.5MB)

typedef __attribute__((ext_vector_type(8))) short bf16x8;
typedef __attribute__((ext_vector_type(4))) float f32x4;

__device__ __forceinline__ unsigned short f2bf(float f) {
  unsigned u = __builtin_bit_cast(unsigned, f);
  u += 0x7fffu + ((u >> 16) & 1u);   // RNE
  return (unsigned short)(u >> 16);
}
__device__ __forceinline__ float bf2f(unsigned short h) {
  unsigned u = ((unsigned)h) << 16;
  return __builtin_bit_cast(float, u);
}

// ---------------- prep_x: xb = bf16(X) ----------------
__global__ __launch_bounds__(256) void prep_x(const float* __restrict__ X,
                                              unsigned short* __restrict__ XB) {
  const size_t base = ((size_t)blockIdx.x * 256 + threadIdx.x) * 16;
  f32x4 a0 = *(const f32x4*)&X[base];
  f32x4 a1 = *(const f32x4*)&X[base + 4];
  f32x4 a2 = *(const f32x4*)&X[base + 8];
  f32x4 a3 = *(const f32x4*)&X[base + 12];
  bf16x8 o0, o1;
#pragma unroll
  for (int j = 0; j < 4; ++j) {
    o0[j] = (short)f2bf(a0[j]);
    o0[4 + j] = (short)f2bf(a1[j]);
    o1[j] = (short)f2bf(a2[j]);
    o1[4 + j] = (short)f2bf(a3[j]);
  }
  *(bf16x8*)&XB[base] = o0;
  *(bf16x8*)&XB[base + 8] = o1;
}

// ---------------- prep_w: WT[c][k] = bf16(Wqkv[k][c] * (c<1024 ? 0.125 : 1)) ----------------
__global__ __launch_bounds__(256) void prep_w(const float* __restrict__ W,
                                              unsigned short* __restrict__ WT) {
  const int t = threadIdx.x;
  const int c0 = blockIdx.x * 128 + (t & 15) * 8;
  const int k0 = blockIdx.y * 128 + (t >> 4) * 8;
  float r[8][8];
#pragma unroll
  for (int j = 0; j < 8; ++j) {
    f32x4 lo = *(const f32x4*)&W[(size_t)(k0 + j) * 1536 + c0];
    f32x4 hi = *(const f32x4*)&W[(size_t)(k0 + j) * 1536 + c0 + 4];
#pragma unroll
    for (int q = 0; q < 4; ++q) {
      r[j][q] = lo[q];
      r[j][4 + q] = hi[q];
    }
  }
#pragma unroll
  for (int i = 0; i < 8; ++i) {
    const float scl = (c0 + i < 1024) ? 0.125f : 1.0f;
    bf16x8 o;
#pragma unroll
    for (int j = 0; j < 8; ++j) o[j] = (short)f2bf(r[j][i] * scl);
    *(bf16x8*)&WT[(size_t)(c0 + i) * 512 + k0] = o;
  }
}

// ---------------- transpose_wout: WoutT[c][k] = bf16(Wout[k][c]) ----------------
__global__ __launch_bounds__(256) void transpose_wout(const float* __restrict__ W,
                                                      unsigned short* __restrict__ WT) {
  const int t = threadIdx.x;
  const int c0 = blockIdx.x * 128 + (t & 15) * 8;
  const int k0 = blockIdx.y * 128 + (t >> 4) * 8;
  float r[8][8];
#pragma unroll
  for (int j = 0; j < 8; ++j) {
    f32x4 lo = *(const f32x4*)&W[(size_t)(k0 + j) * 512 + c0];
    f32x4 hi = *(const f32x4*)&W[(size_t)(k0 + j) * 512 + c0 + 4];
#pragma unroll
    for (int q = 0; q < 4; ++q) {
      r[j][q] = lo[q];
      r[j][4 + q] = hi[q];
    }
  }
#pragma unroll
  for (int i = 0; i < 8; ++i) {
    bf16x8 o;
#pragma unroll
    for (int j = 0; j < 8; ++j) o[j] = (short)f2bf(r[j][i]);
    *(bf16x8*)&WT[(size_t)(c0 + i) * 512 + k0] = o;
  }
}

// ---------------- Transpose V: VT[d][m] = qkv[m][1024+d] ----------------
__global__ __launch_bounds__(256) void transpose_v(const unsigned short* __restrict__ QKV,
                                                   unsigned short* __restrict__ VT) {
  const int t = threadIdx.x;
  const int m0 = blockIdx.x * 128 + (t & 15) * 8;
  const int d0 = blockIdx.y * 128 + (t >> 4) * 8;
  bf16x8 r[8];
#pragma unroll
  for (int j = 0; j < 8; ++j)
    r[j] = *(const bf16x8*)&QKV[(size_t)(m0 + j) * 1536 + 1024 + d0];
#pragma unroll
  for (int i = 0; i < 8; ++i) {
    bf16x8 o;
#pragma unroll
    for (int j = 0; j < 8; ++j) o[j] = r[j][i];
    *(bf16x8*)&VT[(size_t)(d0 + i) * 16384 + m0] = o;
  }
}

// ======== 256x128-tile GEMM body (shared via macro-free repetition) ========
// Per K-step(32): stage A 256x32 (4 b128/thr) + B 128x32 (2 b128/thr);
// wave(wr,wc) reads af[8] (rows wr*128+ai*16+ll) + bfr[4] (cols wc*64+bj*16+ll),
// 32 MFMA into acc[8][4].

#define GEMM_BODY(AG, ASTRIDE, BG, BSTRIDE, KDIM)                                        \
  __shared__ __align__(16) unsigned short Asm[256][40];                                  \
  __shared__ __align__(16) unsigned short Bsm[128][40];                                  \
  const int tid = threadIdx.x;                                                           \
  const int wave = tid >> 6, lane = tid & 63;                                            \
  const int wr = wave >> 1, wc = wave & 1;                                               \
  const int lg = lane >> 4, ll = lane & 15;                                              \
  const int kk = lg * 8;                                                                 \
  const int srow = tid >> 1, sk = (tid & 1) * 16;                                        \
  bf16x8 a0 = *(const bf16x8*)&AG[(size_t)srow * ASTRIDE + sk];                          \
  bf16x8 a1 = *(const bf16x8*)&AG[(size_t)srow * ASTRIDE + sk + 8];                      \
  bf16x8 a2 = *(const bf16x8*)&AG[(size_t)(128 + srow) * ASTRIDE + sk];                  \
  bf16x8 a3 = *(const bf16x8*)&AG[(size_t)(128 + srow) * ASTRIDE + sk + 8];              \
  bf16x8 b0 = *(const bf16x8*)&BG[(size_t)srow * BSTRIDE + sk];                          \
  bf16x8 b1 = *(const bf16x8*)&BG[(size_t)srow * BSTRIDE + sk + 8];                      \
  f32x4 acc[8][4];                                                                       \
  _Pragma("unroll") for (int i = 0; i < 8; ++i) _Pragma("unroll") for (int j = 0; j < 4; \
                                                                       ++j) acc[i][j] =  \
      (f32x4){0.f, 0.f, 0.f, 0.f};                                                       \
  for (int kt = 0; kt < KDIM; kt += 32) {                                                \
    __syncthreads();                                                                     \
    *(bf16x8*)&Asm[srow][sk] = a0;                                                       \
    *(bf16x8*)&Asm[srow][sk + 8] = a1;                                                   \
    *(bf16x8*)&Asm[128 + srow][sk] = a2;                                                 \
    *(bf16x8*)&Asm[128 + srow][sk + 8] = a3;                                             \
    *(bf16x8*)&Bsm[srow][sk] = b0;                                                       \
    *(bf16x8*)&Bsm[srow][sk + 8] = b1;                                                   \
    __syncthreads();                                                                     \
    if (kt + 32 < KDIM) {                                                                \
      a0 = *(const bf16x8*)&AG[(size_t)srow * ASTRIDE + kt + 32 + sk];                   \
      a1 = *(const bf16x8*)&AG[(size_t)srow * ASTRIDE + kt + 32 + sk + 8];               \
      a2 = *(const bf16x8*)&AG[(size_t)(128 + srow) * ASTRIDE + kt + 32 + sk];           \
      a3 = *(const bf16x8*)&AG[(size_t)(128 + srow) * ASTRIDE + kt + 32 + sk + 8];       \
      b0 = *(const bf16x8*)&BG[(size_t)srow * BSTRIDE + kt + 32 + sk];                   \
      b1 = *(const bf16x8*)&BG[(size_t)srow * BSTRIDE + kt + 32 + sk + 8];               \
    }                                                                                    \
    bf16x8 af[8], bfr[4];                                                                \
    _Pragma("unroll") for (int ai = 0; ai < 8; ++ai) af[ai] =                            \
        *(const bf16x8*)&Asm[wr * 128 + ai * 16 + ll][kk];                               \
    _Pragma("unroll") for (int bj = 0; bj < 4; ++bj) bfr[bj] =                           \
        *(const bf16x8*)&Bsm[wc * 64 + bj * 16 + ll][kk];                                \
    _Pragma("unroll") for (int ai = 0; ai < 8; ++ai) _Pragma("unroll") for (int bj = 0;  \
                                                                            bj < 4;      \
                                                                            ++bj)        \
        acc[ai][bj] =                                                                    \
        __builtin_amdgcn_mfma_f32_16x16x32_bf16(af[ai], bfr[bj], acc[ai][bj], 0, 0, 0);  \
  }

// qkv = xb @ WT^T  (scale pre-folded into WT)
__global__ __launch_bounds__(256, 2) void gemm_qkv256(const unsigned short* __restrict__ XB,
                                                      const unsigned short* __restrict__ WT,
                                                      unsigned short* __restrict__ QKV) {
  const int bid = blockIdx.x;
  const int qt = bid / 12, nt = bid - qt * 12;
  const unsigned short* Ag = XB + (size_t)(qt * 256) * 512;
  const unsigned short* Bg = WT + (size_t)(nt * 128) * 512;
  GEMM_BODY(Ag, 512, Bg, 512, 512)
#pragma unroll
  for (int ai = 0; ai < 8; ++ai)
#pragma unroll
    for (int bj = 0; bj < 4; ++bj) {
      const int col = nt * 128 + wc * 64 + bj * 16 + ll;
#pragma unroll
      for (int r = 0; r < 4; ++r) {
        const int row = qt * 256 + wr * 128 + ai * 16 + lg * 4 + r;
        QKV[(size_t)row * 1536 + col] = f2bf(acc[ai][bj][r]);
      }
    }
}

// S[b][q][kv] = Q . K^T (scales pre-folded)
__global__ __launch_bounds__(256, 2) void sgemm256(const unsigned short* __restrict__ QKV,
                                                   unsigned short* __restrict__ S) {
  const int bid = blockIdx.x;
  const int b = bid & 7;  // batch -> XCD
  const int idx = bid >> 3;
  const int kvt = idx & 15, qt = idx >> 4;
  const unsigned short* Ag = QKV + ((size_t)b * 2048 + qt * 256) * 1536;
  const unsigned short* Bg = QKV + ((size_t)b * 2048 + kvt * 128) * 1536 + 512;
  GEMM_BODY(Ag, 1536, Bg, 1536, 512)
  unsigned short* Sg = S + (size_t)b * 2048 * 2048;
#pragma unroll
  for (int ai = 0; ai < 8; ++ai)
#pragma unroll
    for (int bj = 0; bj < 4; ++bj) {
      const int col = kvt * 128 + wc * 64 + bj * 16 + ll;
#pragma unroll
      for (int r = 0; r < 4; ++r) {
        const int row = qt * 256 + wr * 128 + ai * 16 + lg * 4 + r;
        Sg[(size_t)row * 2048 + col] = f2bf(acc[ai][bj][r]);
      }
    }
}

// res = P @ V + x (store to qkvb v-cols)
__global__ __launch_bounds__(256, 2) void pvgemm256(const unsigned short* __restrict__ P,
                                                    const unsigned short* __restrict__ VT,
                                                    const float* __restrict__ X,
                                                    unsigned short* __restrict__ RES) {
  const int bid = blockIdx.x;
  const int b = bid & 7;
  const int idx = bid >> 3;
  const int dt = idx & 3, qt = idx >> 2;
  const unsigned short* Ag = P + (size_t)b * 2048 * 2048 + (size_t)(qt * 256) * 2048;
  const unsigned short* Bg = VT + (size_t)(dt * 128) * 16384 + (size_t)b * 2048;
  GEMM_BODY(Ag, 2048, Bg, 16384, 2048)
#pragma unroll
  for (int ai = 0; ai < 8; ++ai)
#pragma unroll
    for (int bj = 0; bj < 4; ++bj) {
      const int col = dt * 128 + wc * 64 + bj * 16 + ll;
#pragma unroll
      for (int r = 0; r < 4; ++r) {
        const size_t row = (size_t)b * 2048 + qt * 256 + wr * 128 + ai * 16 + lg * 4 + r;
        const float val = acc[ai][bj][r] + X[row * 512 + col];
        RES[row * 1536 + 1024 + col] = f2bf(val);
      }
    }
}

// out = res @ WoutT^T + bout (fp32 out)
__global__ __launch_bounds__(256, 2) void gemm_out256(const unsigned short* __restrict__ A,
                                                      const unsigned short* __restrict__ WT,
                                                      const float* __restrict__ bias,
                                                      float* __restrict__ OUT) {
  const int bid = blockIdx.x;
  const int dt = bid & 3, qt = bid >> 2;
  const unsigned short* Ag = A + (size_t)(qt * 256) * 1536 + 1024;
  const unsigned short* Bg = WT + (size_t)(dt * 128) * 512;
  GEMM_BODY(Ag, 1536, Bg, 512, 512)
#pragma unroll
  for (int ai = 0; ai < 8; ++ai)
#pragma unroll
    for (int bj = 0; bj < 4; ++bj) {
      const int col = dt * 128 + wc * 64 + bj * 16 + ll;
      const float bv = bias[col];
#pragma unroll
      for (int r = 0; r < 4; ++r) {
        const int row = qt * 256 + wr * 128 + ai * 16 + lg * 4 + r;
        OUT[(size_t)row * 512 + col] = acc[ai][bj][r] + bv;
      }
    }
}

// in-place row softmax over 2048 bf16 (one block per row)
__global__ __launch_bounds__(256) void softmax_rows(unsigned short* __restrict__ S) {
  __shared__ float red[8];
  const int tid = threadIdx.x;
  const int wave = tid >> 6, lane = tid & 63;
  unsigned short* row = S + (size_t)blockIdx.x * 2048;

  bf16x8 v = *(const bf16x8*)&row[tid * 8];
  float f[8];
#pragma unroll
  for (int j = 0; j < 8; ++j) f[j] = bf2f((unsigned short)v[j]);

  float mx = f[0];
#pragma unroll
  for (int j = 1; j < 8; ++j) mx = fmaxf(mx, f[j]);
  mx = fmaxf(mx, __shfl_xor(mx, 1));
  mx = fmaxf(mx, __shfl_xor(mx, 2));
  mx = fmaxf(mx, __shfl_xor(mx, 4));
  mx = fmaxf(mx, __shfl_xor(mx, 8));
  mx = fmaxf(mx, __shfl_xor(mx, 16));
  mx = fmaxf(mx, __shfl_xor(mx, 32));
  if (lane == 0) red[wave] = mx;
  __syncthreads();
  mx = fmaxf(fmaxf(red[0], red[1]), fmaxf(red[2], red[3]));

  float s = 0.f;
#pragma unroll
  for (int j = 0; j < 8; ++j) {
    f[j] = __expf(f[j] - mx);
    s += f[j];
  }
  s += __shfl_xor(s, 1);
  s += __shfl_xor(s, 2);
  s += __shfl_xor(s, 4);
  s += __shfl_xor(s, 8);
  s += __shfl_xor(s, 16);
  s += __shfl_xor(s, 32);
  if (lane == 0) red[4 + wave] = s;
  __syncthreads();
  s = (red[4] + red[5]) + (red[6] + red[7]);
  const float inv = 1.0f / s;
#pragma unroll
  for (int j = 0; j < 8; ++j) v[j] = (short)f2bf(f[j] * inv);
  *(bf16x8*)&row[tid * 8] = v;
}

extern "C" void kernel_launch(void* const* d_in, const int* in_sizes, int n_in,
                              void* d_out, int out_size, void* d_ws, size_t ws_size,
                              hipStream_t stream) {
  const float* x = (const float*)d_in[0];     // [8,2048,512]
  const float* Wqkv = (const float*)d_in[1];  // [512,1536]
  const float* Wout = (const float*)d_in[2];  // [512,512]
  const float* bout = (const float*)d_in[3];  // [512]
  float* out = (float*)d_out;                 // [8,2048,512] fp32

  unsigned short* qkvb = (unsigned short*)d_ws;        // 16384*1536 bf16 = 50.3MB
  unsigned short* VT = qkvb + (size_t)16384 * 1536;    // 512*16384  bf16 = 16.8MB
  unsigned short* S = VT + (size_t)512 * 16384;        // 8*2048*2048 bf16 = 67.1MB
  unsigned short* xb = S;                              // bf16 X (dead before sgemm)
  unsigned short* WT = S + (size_t)16384 * 512;        // Wqkv^T scaled (dead before sgemm)
  unsigned short* WoutT = VT;                          // VT dead after pvgemm

  prep_x<<<2048, 256, 0, stream>>>(x, xb);
  prep_w<<<dim3(12, 4), 256, 0, stream>>>(Wqkv, WT);
  gemm_qkv256<<<768, 256, 0, stream>>>(xb, WT, qkvb);
  transpose_v<<<dim3(128, 4), 256, 0, stream>>>(qkvb, VT);
  sgemm256<<<1024, 256, 0, stream>>>(qkvb, S);
  softmax_rows<<<16384, 256, 0, stream>>>(S);
  pvgemm256<<<256, 256, 0, stream>>>(S, VT, x, qkvb);
  transpose_wout<<<dim3(4, 4), 256, 0, stream>>>(Wout, WoutT);
  gemm_out256<<<256, 256, 0, stream>>>(qkvb, WoutT, bout, out);
}

// Round 8
// 201.035 us; speedup vs baseline: 1.0589x; 1.0589x over previous
//
#include <hip/hip_runtime.h>
#include <hip/hip_bf16.h>

// MSSA: x(8,2048,512) -> qkv = x@Wqkv ; scores = (q*s)@(k*s)^T over FULL 512 dims ;
// attn = softmax ; out = attn@v ; result = (out + x)@Wout + bout
//
// All GEMMs: m97-structure 128x128 tile (guide ladder step 3 = 874 TF):
//   BK=32, 4 waves x (64x64 acc[4][4]), LINEAR 16KB LDS (no pad -- required by
//   global_load_lds, conflicts off critical path in 2-phase regime per T2 gate),
//   staging via 4x global_load_lds dwordx4 per wave (no VGPR round trip),
//   2 barriers per K-step.
//
// Workspace (128 MiB):
//   qkvb : bf16 [16384][1536]  q(x0.125)|k(x0.125)|v ; v-cols dead after transpose_v
//                              -> reused for res = bf16(attn_out + x)
//   VT   : bf16 [512][16384]   V transposed; dead after pvgemm -> reused for WoutT
//   S    : bf16 [8][2048][2048] scores/P; pre-sgemm holds xb (16.8MB) + WT (1.5MB)
//
// LESSONS: R3/R4: 512-thr blocks cap unified regs at 256/wave -> spill.
// R7: per-wave tile growth doesn't raise FLOP/LDS-byte much and shrinking the
// grid to 1 block/CU exposes latency; keep >=2 blocks/CU and fix staging instead.

typedef __attribute__((ext_vector_type(8))) short bf16x8;
typedef __attribute__((ext_vector_type(4))) float f32x4;

__device__ __forceinline__ unsigned short f2bf(float f) {
  unsigned u = __builtin_bit_cast(unsigned, f);
  u += 0x7fffu + ((u >> 16) & 1u);   // RNE
  return (unsigned short)(u >> 16);
}
__device__ __forceinline__ float bf2f(unsigned short h) {
  unsigned u = ((unsigned)h) << 16;
  return __builtin_bit_cast(float, u);
}

// async global->LDS, 16B per lane; LDS dest = uniform base + lane*16 (HW rule)
__device__ __forceinline__ void async16(const unsigned short* g, unsigned short* l) {
  __builtin_amdgcn_global_load_lds(
      (const __attribute__((address_space(1))) unsigned int*)g,
      (__attribute__((address_space(3))) unsigned int*)l, 16, 0, 0);
}

// ---------------- prep_x: xb = bf16(X) ----------------
__global__ __launch_bounds__(256) void prep_x(const float* __restrict__ X,
                                              unsigned short* __restrict__ XB) {
  const size_t base = ((size_t)blockIdx.x * 256 + threadIdx.x) * 16;
  f32x4 a0 = *(const f32x4*)&X[base];
  f32x4 a1 = *(const f32x4*)&X[base + 4];
  f32x4 a2 = *(const f32x4*)&X[base + 8];
  f32x4 a3 = *(const f32x4*)&X[base + 12];
  bf16x8 o0, o1;
#pragma unroll
  for (int j = 0; j < 4; ++j) {
    o0[j] = (short)f2bf(a0[j]);
    o0[4 + j] = (short)f2bf(a1[j]);
    o1[j] = (short)f2bf(a2[j]);
    o1[4 + j] = (short)f2bf(a3[j]);
  }
  *(bf16x8*)&XB[base] = o0;
  *(bf16x8*)&XB[base + 8] = o1;
}

// ---------------- prep_w: WT[c][k] = bf16(Wqkv[k][c] * (c<1024 ? 0.125 : 1)) ----------------
__global__ __launch_bounds__(256) void prep_w(const float* __restrict__ W,
                                              unsigned short* __restrict__ WT) {
  const int t = threadIdx.x;
  const int c0 = blockIdx.x * 128 + (t & 15) * 8;
  const int k0 = blockIdx.y * 128 + (t >> 4) * 8;
  float r[8][8];
#pragma unroll
  for (int j = 0; j < 8; ++j) {
    f32x4 lo = *(const f32x4*)&W[(size_t)(k0 + j) * 1536 + c0];
    f32x4 hi = *(const f32x4*)&W[(size_t)(k0 + j) * 1536 + c0 + 4];
#pragma unroll
    for (int q = 0; q < 4; ++q) {
      r[j][q] = lo[q];
      r[j][4 + q] = hi[q];
    }
  }
#pragma unroll
  for (int i = 0; i < 8; ++i) {
    const float scl = (c0 + i < 1024) ? 0.125f : 1.0f;
    bf16x8 o;
#pragma unroll
    for (int j = 0; j < 8; ++j) o[j] = (short)f2bf(r[j][i] * scl);
    *(bf16x8*)&WT[(size_t)(c0 + i) * 512 + k0] = o;
  }
}

// ---------------- transpose_wout: WoutT[c][k] = bf16(Wout[k][c]) ----------------
__global__ __launch_bounds__(256) void transpose_wout(const float* __restrict__ W,
                                                      unsigned short* __restrict__ WT) {
  const int t = threadIdx.x;
  const int c0 = blockIdx.x * 128 + (t & 15) * 8;
  const int k0 = blockIdx.y * 128 + (t >> 4) * 8;
  float r[8][8];
#pragma unroll
  for (int j = 0; j < 8; ++j) {
    f32x4 lo = *(const f32x4*)&W[(size_t)(k0 + j) * 512 + c0];
    f32x4 hi = *(const f32x4*)&W[(size_t)(k0 + j) * 512 + c0 + 4];
#pragma unroll
    for (int q = 0; q < 4; ++q) {
      r[j][q] = lo[q];
      r[j][4 + q] = hi[q];
    }
  }
#pragma unroll
  for (int i = 0; i < 8; ++i) {
    bf16x8 o;
#pragma unroll
    for (int j = 0; j < 8; ++j) o[j] = (short)f2bf(r[j][i]);
    *(bf16x8*)&WT[(size_t)(c0 + i) * 512 + k0] = o;
  }
}

// ---------------- Transpose V: VT[d][m] = qkv[m][1024+d] ----------------
__global__ __launch_bounds__(256) void transpose_v(const unsigned short* __restrict__ QKV,
                                                   unsigned short* __restrict__ VT) {
  const int t = threadIdx.x;
  const int m0 = blockIdx.x * 128 + (t & 15) * 8;
  const int d0 = blockIdx.y * 128 + (t >> 4) * 8;
  bf16x8 r[8];
#pragma unroll
  for (int j = 0; j < 8; ++j)
    r[j] = *(const bf16x8*)&QKV[(size_t)(m0 + j) * 1536 + 1024 + d0];
#pragma unroll
  for (int i = 0; i < 8; ++i) {
    bf16x8 o;
#pragma unroll
    for (int j = 0; j < 8; ++j) o[j] = r[j][i];
    *(bf16x8*)&VT[(size_t)(d0 + i) * 16384 + m0] = o;
  }
}

// ======== m97-structure 128x128 GEMM body ========
// LDS linear [128][32] (8KB) per operand. Per K-step per wave: 4 global_load_lds
// (A rows wave*32+i*16+lane/4, 16B each), barrier, 8 ds_read_b128, 16 MFMA, barrier.

#define GEMM97_BODY(AG, ASTR, BG, BSTR, KDIM)                                            \
  __shared__ __align__(16) unsigned short Asm[4096];                                     \
  __shared__ __align__(16) unsigned short Bsm[4096];                                     \
  const int tid = threadIdx.x;                                                           \
  const int wave = tid >> 6, lane = tid & 63;                                            \
  const int wr = wave >> 1, wc = wave & 1;                                               \
  const int lg = lane >> 4, ll = lane & 15;                                              \
  const int kk = lg * 8;                                                                 \
  const int srow = wave * 32 + (lane >> 2); /* staging row, +16 for 2nd issue */         \
  const int scol = (lane & 3) * 8;          /* staging col (elements) */                 \
  f32x4 acc[4][4];                                                                       \
  _Pragma("unroll") for (int i = 0; i < 4; ++i) _Pragma("unroll") for (int j = 0; j < 4; \
                                                                       ++j) acc[i][j] =  \
      (f32x4){0.f, 0.f, 0.f, 0.f};                                                       \
  for (int kt = 0; kt < KDIM; kt += 32) {                                                \
    async16(&AG[(size_t)srow * ASTR + kt + scol], &Asm[wave * 1024]);                    \
    async16(&AG[(size_t)(srow + 16) * ASTR + kt + scol], &Asm[wave * 1024 + 512]);       \
    async16(&BG[(size_t)srow * BSTR + kt + scol], &Bsm[wave * 1024]);                    \
    async16(&BG[(size_t)(srow + 16) * BSTR + kt + scol], &Bsm[wave * 1024 + 512]);       \
    __syncthreads(); /* drains vmcnt -> staged tile visible */                           \
    bf16x8 af[4], bfr[4];                                                                \
    _Pragma("unroll") for (int ai = 0; ai < 4; ++ai) af[ai] =                            \
        *(const bf16x8*)&Asm[(wr * 64 + ai * 16 + ll) * 32 + kk];                        \
    _Pragma("unroll") for (int bj = 0; bj < 4; ++bj) bfr[bj] =                           \
        *(const bf16x8*)&Bsm[(wc * 64 + bj * 16 + ll) * 32 + kk];                        \
    _Pragma("unroll") for (int ai = 0; ai < 4; ++ai) _Pragma("unroll") for (int bj = 0;  \
                                                                            bj < 4;      \
                                                                            ++bj)        \
        acc[ai][bj] =                                                                    \
        __builtin_amdgcn_mfma_f32_16x16x32_bf16(af[ai], bfr[bj], acc[ai][bj], 0, 0, 0);  \
    __syncthreads(); /* all reads done before next issue overwrites */                   \
  }

// qkv = xb @ WT^T (scale pre-folded into WT)
__global__ __launch_bounds__(256) void gemm_qkv97(const unsigned short* __restrict__ XB,
                                                  const unsigned short* __restrict__ WT,
                                                  unsigned short* __restrict__ QKV) {
  const int bid = blockIdx.x;
  const int qt = bid / 12, nt = bid - qt * 12;
  const unsigned short* Ag = XB + (size_t)(qt * 128) * 512;
  const unsigned short* Bg = WT + (size_t)(nt * 128) * 512;
  GEMM97_BODY(Ag, 512, Bg, 512, 512)
#pragma unroll
  for (int ai = 0; ai < 4; ++ai)
#pragma unroll
    for (int bj = 0; bj < 4; ++bj) {
      const int col = nt * 128 + wc * 64 + bj * 16 + ll;
#pragma unroll
      for (int r = 0; r < 4; ++r) {
        const int row = qt * 128 + wr * 64 + ai * 16 + lg * 4 + r;
        QKV[(size_t)row * 1536 + col] = f2bf(acc[ai][bj][r]);
      }
    }
}

// S[b][q][kv] = Q . K^T (scales pre-folded)
__global__ __launch_bounds__(256) void sgemm97(const unsigned short* __restrict__ QKV,
                                               unsigned short* __restrict__ S) {
  const int bid = blockIdx.x;
  const int b = bid & 7;  // batch -> XCD (L2 locality)
  const int idx = bid >> 3;
  const int kvt = idx & 15, qt = idx >> 4;
  const unsigned short* Ag = QKV + ((size_t)b * 2048 + qt * 128) * 1536;
  const unsigned short* Bg = QKV + ((size_t)b * 2048 + kvt * 128) * 1536 + 512;
  GEMM97_BODY(Ag, 1536, Bg, 1536, 512)
  unsigned short* Sg = S + (size_t)b * 2048 * 2048;
#pragma unroll
  for (int ai = 0; ai < 4; ++ai)
#pragma unroll
    for (int bj = 0; bj < 4; ++bj) {
      const int col = kvt * 128 + wc * 64 + bj * 16 + ll;
#pragma unroll
      for (int r = 0; r < 4; ++r) {
        const int row = qt * 128 + wr * 64 + ai * 16 + lg * 4 + r;
        Sg[(size_t)row * 2048 + col] = f2bf(acc[ai][bj][r]);
      }
    }
}

// res = P @ V + x (store to qkvb v-cols)
__global__ __launch_bounds__(256) void pvgemm97(const unsigned short* __restrict__ P,
                                                const unsigned short* __restrict__ VT,
                                                const float* __restrict__ X,
                                                unsigned short* __restrict__ RES) {
  const int bid = blockIdx.x;
  const int b = bid & 7;
  const int idx = bid >> 3;
  const int dt = idx & 3, qt = idx >> 2;
  const unsigned short* Ag = P + (size_t)b * 2048 * 2048 + (size_t)(qt * 128) * 2048;
  const unsigned short* Bg = VT + (size_t)(dt * 128) * 16384 + (size_t)b * 2048;
  GEMM97_BODY(Ag, 2048, Bg, 16384, 2048)
#pragma unroll
  for (int ai = 0; ai < 4; ++ai)
#pragma unroll
    for (int bj = 0; bj < 4; ++bj) {
      const int col = dt * 128 + wc * 64 + bj * 16 + ll;
#pragma unroll
      for (int r = 0; r < 4; ++r) {
        const size_t row = (size_t)b * 2048 + qt * 128 + wr * 64 + ai * 16 + lg * 4 + r;
        const float val = acc[ai][bj][r] + X[row * 512 + col];
        RES[row * 1536 + 1024 + col] = f2bf(val);
      }
    }
}

// out = res @ WoutT^T + bout (fp32 out)
__global__ __launch_bounds__(256) void gemm_out97(const unsigned short* __restrict__ A,
                                                  const unsigned short* __restrict__ WT,
                                                  const float* __restrict__ bias,
                                                  float* __restrict__ OUT) {
  const int bid = blockIdx.x;
  const int dt = bid & 3, qt = bid >> 2;
  const unsigned short* Ag = A + (size_t)(qt * 128) * 1536 + 1024;
  const unsigned short* Bg = WT + (size_t)(dt * 128) * 512;
  GEMM97_BODY(Ag, 1536, Bg, 512, 512)
#pragma unroll
  for (int ai = 0; ai < 4; ++ai)
#pragma unroll
    for (int bj = 0; bj < 4; ++bj) {
      const int col = dt * 128 + wc * 64 + bj * 16 + ll;
      const float bv = bias[col];
#pragma unroll
      for (int r = 0; r < 4; ++r) {
        const int row = qt * 128 + wr * 64 + ai * 16 + lg * 4 + r;
        OUT[(size_t)row * 512 + col] = acc[ai][bj][r] + bv;
      }
    }
}

// in-place row softmax over 2048 bf16 (one block per row)
__global__ __launch_bounds__(256) void softmax_rows(unsigned short* __restrict__ S) {
  __shared__ float red[8];
  const int tid = threadIdx.x;
  const int wave = tid >> 6, lane = tid & 63;
  unsigned short* row = S + (size_t)blockIdx.x * 2048;

  bf16x8 v = *(const bf16x8*)&row[tid * 8];
  float f[8];
#pragma unroll
  for (int j = 0; j < 8; ++j) f[j] = bf2f((unsigned short)v[j]);

  float mx = f[0];
#pragma unroll
  for (int j = 1; j < 8; ++j) mx = fmaxf(mx, f[j]);
  mx = fmaxf(mx, __shfl_xor(mx, 1));
  mx = fmaxf(mx, __shfl_xor(mx, 2));
  mx = fmaxf(mx, __shfl_xor(mx, 4));
  mx = fmaxf(mx, __shfl_xor(mx, 8));
  mx = fmaxf(mx, __shfl_xor(mx, 16));
  mx = fmaxf(mx, __shfl_xor(mx, 32));
  if (lane == 0) red[wave] = mx;
  __syncthreads();
  mx = fmaxf(fmaxf(red[0], red[1]), fmaxf(red[2], red[3]));

  float s = 0.f;
#pragma unroll
  for (int j = 0; j < 8; ++j) {
    f[j] = __expf(f[j] - mx);
    s += f[j];
  }
  s += __shfl_xor(s, 1);
  s += __shfl_xor(s, 2);
  s += __shfl_xor(s, 4);
  s += __shfl_xor(s, 8);
  s += __shfl_xor(s, 16);
  s += __shfl_xor(s, 32);
  if (lane == 0) red[4 + wave] = s;
  __syncthreads();
  s = (red[4] + red[5]) + (red[6] + red[7]);
  const float inv = 1.0f / s;
#pragma unroll
  for (int j = 0; j < 8; ++j) v[j] = (short)f2bf(f[j] * inv);
  *(bf16x8*)&row[tid * 8] = v;
}

extern "C" void kernel_launch(void* const* d_in, const int* in_sizes, int n_in,
                              void* d_out, int out_size, void* d_ws, size_t ws_size,
                              hipStream_t stream) {
  const float* x = (const float*)d_in[0];     // [8,2048,512]
  const float* Wqkv = (const float*)d_in[1];  // [512,1536]
  const float* Wout = (const float*)d_in[2];  // [512,512]
  const float* bout = (const float*)d_in[3];  // [512]
  float* out = (float*)d_out;                 // [8,2048,512] fp32

  unsigned short* qkvb = (unsigned short*)d_ws;        // 16384*1536 bf16 = 50.3MB
  unsigned short* VT = qkvb + (size_t)16384 * 1536;    // 512*16384  bf16 = 16.8MB
  unsigned short* S = VT + (size_t)512 * 16384;        // 8*2048*2048 bf16 = 67.1MB
  unsigned short* xb = S;                              // bf16 X (dead before sgemm)
  unsigned short* WT = S + (size_t)16384 * 512;        // Wqkv^T scaled (dead before sgemm)
  unsigned short* WoutT = VT;                          // VT dead after pvgemm

  prep_x<<<2048, 256, 0, stream>>>(x, xb);
  prep_w<<<dim3(12, 4), 256, 0, stream>>>(Wqkv, WT);
  gemm_qkv97<<<1536, 256, 0, stream>>>(xb, WT, qkvb);
  transpose_v<<<dim3(128, 4), 256, 0, stream>>>(qkvb, VT);
  sgemm97<<<2048, 256, 0, stream>>>(qkvb, S);
  softmax_rows<<<16384, 256, 0, stream>>>(S);
  pvgemm97<<<512, 256, 0, stream>>>(S, VT, x, qkvb);
  transpose_wout<<<dim3(4, 4), 256, 0, stream>>>(Wout, WoutT);
  gemm_out97<<<512, 256, 0, stream>>>(qkvb, WoutT, bout, out);
}